// Round 18
// baseline (92376.733 us; speedup 1.0000x reference)
//
#include <hip/hip_runtime.h>
#include <cstdint>
#include <cstddef>
#include <climits>

#define Hdim 1024
#define Vdim 32000
#define Lq 64
#define Nrows 128
#define TMAX 64
#define NEGF (-1e30f)

// lower flat index wins ties (jax.lax.top_k stable semantics)
__device__ __forceinline__ bool betterf(float av, int ai, float bv, int bi) {
  return (av > bv) || (av == bv && ai < bi);
}

// ---- XLA CPU tanh f32 ----
__device__ __forceinline__ float tanh_xla(float x) {
  float ax = fabsf(x);
  float xc = fminf(fmaxf(x, -7.90531110763549805f), 7.90531110763549805f);
  float x2 = __fmul_rn(xc, xc);
  float p = -2.76076847742355e-16f;
  p = fmaf(p, x2, 2.00018790482477e-13f);
  p = fmaf(p, x2, -8.60467152213735e-11f);
  p = fmaf(p, x2, 5.12229709037114e-08f);
  p = fmaf(p, x2, 1.48572235717979e-05f);
  p = fmaf(p, x2, 6.37261928875436e-04f);
  p = fmaf(p, x2, 4.89352455891786e-03f);
  p = __fmul_rn(xc, p);
  float q = 1.19825839466702e-06f;
  q = fmaf(q, x2, 1.18534705686654e-04f);
  q = fmaf(q, x2, 2.26843463243900e-03f);
  q = fmaf(q, x2, 4.89352518554385e-03f);
  float r = __fdiv_rn(p, q);
  return (ax < 0.0004f) ? x : r;
}

// ---- XLA LogisticExpander ----
__device__ __forceinline__ float sigmoid_xla(float x) {
  return __fadd_rn(0.5f, __fmul_rn(0.5f, tanh_xla(__fmul_rn(0.5f, x))));
}

// ---- Eigen/Cephes pexp f32 ----
__device__ __forceinline__ float exp_xla(float x) {
  x = fminf(x, 88.3762626647950f);
  x = fmaxf(x, -88.3762626647949f);
  float m = floorf(fmaf(x, 1.44269504088896341f, 0.5f));
  float r = fmaf(m, -0.693359375f, x);
  r = fmaf(m, 2.12194440e-4f, r);
  float r2 = __fmul_rn(r, r);
  float p = 1.9875691500e-4f;
  p = fmaf(p, r, 1.3981999507e-3f);
  p = fmaf(p, r, 8.3334519073e-3f);
  p = fmaf(p, r, 4.1665795894e-2f);
  p = fmaf(p, r, 1.6666665459e-1f);
  p = fmaf(p, r, 5.0000001201e-1f);
  p = fmaf(p, r2, r);
  p = __fadd_rn(p, 1.0f);
  int n = (int)m;
  float two_n = __int_as_float((n + 127) << 23);
  return __fmul_rn(p, two_n);
}

// ---- Cephes logf ----
__device__ __forceinline__ float log_xla(float x) {
  int ix = __float_as_int(x);
  int e = ((ix >> 23) & 0xFF) - 126;
  float m = __int_as_float((ix & 0x007FFFFF) | 0x3F000000);
  if (m < 0.707106781186547524f) { e -= 1; m = __fadd_rn(m, m); }
  m = __fsub_rn(m, 1.0f);
  float z = __fmul_rn(m, m);
  float p = 7.0376836292e-2f;
  p = fmaf(p, m, -1.1514610310e-1f);
  p = fmaf(p, m, 1.1676998740e-1f);
  p = fmaf(p, m, -1.2420140846e-1f);
  p = fmaf(p, m, 1.4249322787e-1f);
  p = fmaf(p, m, -1.6668057665e-1f);
  p = fmaf(p, m, 2.0000714765e-1f);
  p = fmaf(p, m, -2.4999993993e-1f);
  p = fmaf(p, m, 3.3333331174e-1f);
  float ef = (float)e;
  float y = __fmul_rn(m, __fmul_rn(z, p));
  y = fmaf(ef, -2.12194440e-4f, y);
  y = fmaf(z, -0.5f, y);
  float res = __fadd_rn(m, y);
  res = fmaf(ef, 0.693359375f, res);
  return res;
}

// B-column XOR swizzle (16B-aligned permutation)
__device__ __forceinline__ int bswz(int col) {
  return col ^ (((col >> 5) & 3) << 2);
}

// ---- templated GEMM body (256 threads, r15 structure) ----
template <int MT, int NT>
__device__ __forceinline__ void gemm_body(
    const float* __restrict__ A, int lda, const int* __restrict__ rowmap,
    const float* __restrict__ B, int ldb, const float* __restrict__ bias,
    float* __restrict__ C, int ldc, int K, int act, int n0, int m0)
{
  constexpr int RM = MT / 16, RN = NT / 16;
  constexpr int PA = MT + 4, PB = NT + 4;
  __shared__ float As[32][PA];
  __shared__ float Bs[32][PB];
  __shared__ int rows[MT];
  const int t = threadIdx.x;
  if (t < MT) rows[t] = rowmap ? rowmap[m0 + t] : (m0 + t);
  __syncthreads();
  const int tm = t >> 4, tn = t & 15;
  float acc[RM][RN] = {};
  for (int kt = 0; kt < K; kt += 32) {
#pragma unroll
    for (int i = 0; i < MT / 32; ++i) {
      int idx = t + i * 256;
      int m = idx >> 3, k4 = idx & 7;
      float4 v = *reinterpret_cast<const float4*>(
          &A[(size_t)rows[m] * lda + (size_t)(kt + k4 * 4)]);
      As[k4 * 4 + 0][m] = v.x;
      As[k4 * 4 + 1][m] = v.y;
      As[k4 * 4 + 2][m] = v.z;
      As[k4 * 4 + 3][m] = v.w;
    }
#pragma unroll
    for (int i = 0; i < NT / 32; ++i) {
      int idx = t + i * 256;
      int kk = idx / (NT / 4), n4 = idx % (NT / 4);
      float4 v = *reinterpret_cast<const float4*>(
          &B[(size_t)(kt + kk) * ldb + (size_t)(n0 + n4 * 4)]);
      *reinterpret_cast<float4*>(&Bs[kk][bswz(n4 * 4)]) = v;
    }
    __syncthreads();
#pragma unroll
    for (int kk = 0; kk < 32; ++kk) {
      float a[RM], bb[RN];
      if constexpr (RM == 2) {
        float2 v = *reinterpret_cast<const float2*>(&As[kk][tm * 2]);
        a[0] = v.x; a[1] = v.y;
      } else {
#pragma unroll
        for (int c = 0; c < RM / 4; ++c) {
          float4 v = *reinterpret_cast<const float4*>(&As[kk][tm * RM + c * 4]);
          a[c * 4 + 0] = v.x; a[c * 4 + 1] = v.y;
          a[c * 4 + 2] = v.z; a[c * 4 + 3] = v.w;
        }
      }
      if constexpr (RN == 2) {
        float2 v = *reinterpret_cast<const float2*>(&Bs[kk][tn * 2]);
        bb[0] = v.x; bb[1] = v.y;
      } else {
#pragma unroll
        for (int c = 0; c < RN / 4; ++c) {
          float4 v = *reinterpret_cast<const float4*>(
              &Bs[kk][bswz(tn * RN + c * 4)]);
          bb[c * 4 + 0] = v.x; bb[c * 4 + 1] = v.y;
          bb[c * 4 + 2] = v.z; bb[c * 4 + 3] = v.w;
        }
      }
#pragma unroll
      for (int i = 0; i < RM; ++i)
#pragma unroll
        for (int j = 0; j < RN; ++j)
          acc[i][j] = fmaf(a[i], bb[j], acc[i][j]);
    }
    __syncthreads();
  }
#pragma unroll
  for (int i = 0; i < RM; ++i) {
    int m = m0 + tm * RM + i;
#pragma unroll
    for (int j = 0; j < RN; ++j) {
      int n = n0 + tn * RN + j;
      float v = acc[i][j];
      if (bias) v = __fadd_rn(v, bias[n]);
      if (act == 1) v = tanh_xla(v);
      C[(size_t)m * ldc + n] = v;
    }
  }
}

// ---- logits GEMM: r15 structure (128x128, 8x8 micro, 256 threads) + T14
// async-STAGE split: issue tile k+1 global loads BEFORE computing tile k;
// write regs->LDS after the read-barrier. Single LDS buffer, same barriers.
// Per-output sequential-k FMA chain identical -> bit-exact.
__global__ __launch_bounds__(256) void sgemm_logits(
    const float* __restrict__ A, const float* __restrict__ B,
    const float* __restrict__ bias, float* __restrict__ C)
{
  constexpr int RM = 8, RN = 8;
  __shared__ float As[32][132];
  __shared__ float Bs[32][132];
  const int t = threadIdx.x;
  const int n0 = blockIdx.x * 128;
  const int tm = t >> 4, tn = t & 15;
  float4 rA[4], rB[4];

  auto load_regs = [&](int kt) {
#pragma unroll
    for (int i = 0; i < 4; ++i) {
      int idx = t + i * 256;
      int m = idx >> 3, k4 = idx & 7;
      rA[i] = *reinterpret_cast<const float4*>(
          &A[(size_t)m * 1024 + (size_t)(kt + k4 * 4)]);
    }
#pragma unroll
    for (int i = 0; i < 4; ++i) {
      int idx = t + i * 256;
      int kk = idx >> 5, n4 = idx & 31;
      rB[i] = *reinterpret_cast<const float4*>(
          &B[(size_t)(kt + kk) * 32000 + (size_t)(n0 + n4 * 4)]);
    }
  };
  auto store_lds = [&]() {
#pragma unroll
    for (int i = 0; i < 4; ++i) {
      int idx = t + i * 256;
      int m = idx >> 3, k4 = idx & 7;
      As[k4 * 4 + 0][m] = rA[i].x;
      As[k4 * 4 + 1][m] = rA[i].y;
      As[k4 * 4 + 2][m] = rA[i].z;
      As[k4 * 4 + 3][m] = rA[i].w;
    }
#pragma unroll
    for (int i = 0; i < 4; ++i) {
      int idx = t + i * 256;
      int kk = idx >> 5, n4 = idx & 31;
      *reinterpret_cast<float4*>(&Bs[kk][bswz(n4 * 4)]) = rB[i];
    }
  };

  float acc[RM][RN] = {};
  load_regs(0);
  store_lds();
  __syncthreads();
  for (int tile = 0; tile < 32; ++tile) {
    if (tile < 31) load_regs((tile + 1) * 32);   // issue early: hides under FMA
#pragma unroll
    for (int kk = 0; kk < 32; ++kk) {
      float a[RM], bb[RN];
#pragma unroll
      for (int c = 0; c < 2; ++c) {
        float4 v = *reinterpret_cast<const float4*>(&As[kk][tm * RM + c * 4]);
        a[c * 4 + 0] = v.x; a[c * 4 + 1] = v.y;
        a[c * 4 + 2] = v.z; a[c * 4 + 3] = v.w;
      }
#pragma unroll
      for (int c = 0; c < 2; ++c) {
        float4 v = *reinterpret_cast<const float4*>(
            &Bs[kk][bswz(tn * RN + c * 4)]);
        bb[c * 4 + 0] = v.x; bb[c * 4 + 1] = v.y;
        bb[c * 4 + 2] = v.z; bb[c * 4 + 3] = v.w;
      }
#pragma unroll
      for (int i = 0; i < RM; ++i)
#pragma unroll
        for (int j = 0; j < RN; ++j)
          acc[i][j] = fmaf(a[i], bb[j], acc[i][j]);
    }
    __syncthreads();                    // all waves done reading LDS
    if (tile < 31) store_lds();         // write late
    __syncthreads();                    // LDS ready for next tile
  }
#pragma unroll
  for (int i = 0; i < RM; ++i) {
    int m = tm * RM + i;
#pragma unroll
    for (int j = 0; j < RN; ++j) {
      int n = n0 + tn * RN + j;
      float v = __fadd_rn(acc[i][j], bias[n]);
      C[(size_t)m * 32000 + n] = v;
    }
  }
}

// both gate GEMMs in one launch: 32x64 tiles -> grid (48,4,2) = 384 blocks
__global__ __launch_bounds__(256) void gates_gemm(
    const float* __restrict__ emb, const int* __restrict__ symmap,
    const float* __restrict__ W_ih,
    const float* __restrict__ hprev, const int* __restrict__ hmap,
    const float* __restrict__ W_hh,
    float* __restrict__ gA, float* __restrict__ gB)
{
  if (blockIdx.z == 0)
    gemm_body<32, 64>(emb, 1024, symmap, W_ih, 3072, nullptr, gA, 3072, 1024, 0,
                      blockIdx.x * 64, blockIdx.y * 32);
  else
    gemm_body<32, 64>(hprev, 1024, hmap, W_hh, 3072, nullptr, gB, 3072, 1024, 0,
                      blockIdx.x * 64, blockIdx.y * 32);
}

// W_c GEMM + tanh: 32x32 tiles -> grid (32,4) = 128 blocks
__global__ __launch_bounds__(256) void sgemm_wc(
    const float* __restrict__ A2, const float* __restrict__ W_c,
    float* __restrict__ obuf)
{
  gemm_body<32, 32>(A2, 2048, nullptr, W_c, 1024, nullptr, obuf, 1024, 2048, 1,
                    blockIdx.x * 32, blockIdx.y * 32);
}

// ---- fused GRU gates + attention ----
__global__ __launch_bounds__(256) void gru_attn(
    const float* __restrict__ gA, const float* __restrict__ gB,
    const float* __restrict__ b_ih, const float* __restrict__ b_hh,
    const float* __restrict__ hprev, const int* __restrict__ hmap,
    const float* __restrict__ q_enc, const int* __restrict__ q_len,
    float* __restrict__ hout, float* __restrict__ A2)
{
  int n = blockIdx.x;
  int b = n >> 3;
  int t = threadIdx.x;
  __shared__ float hsh[Hdim];
  __shared__ float att[Lq];
  __shared__ float ebuf[Lq];
  __shared__ float s_mx, s_sum;

  {
    int row = hmap[n];
    const float* hp = hprev + (size_t)row * Hdim;
    const float* a = gA + (size_t)n * 3 * Hdim;
    const float* g = gB + (size_t)n * 3 * Hdim;
    for (int j = t; j < Hdim; j += 256) {
      float xr = __fadd_rn(a[j],            b_ih[j]);
      float xz = __fadd_rn(a[Hdim + j],     b_ih[Hdim + j]);
      float xn = __fadd_rn(a[2 * Hdim + j], b_ih[2 * Hdim + j]);
      float hr = __fadd_rn(g[j],            b_hh[j]);
      float hz = __fadd_rn(g[Hdim + j],     b_hh[Hdim + j]);
      float hn = __fadd_rn(g[2 * Hdim + j], b_hh[2 * Hdim + j]);
      float r = sigmoid_xla(__fadd_rn(xr, hr));
      float z = sigmoid_xla(__fadd_rn(xz, hz));
      float t1 = __fmul_rn(r, hn);
      float nn = tanh_xla(__fadd_rn(xn, t1));
      float u1 = __fsub_rn(1.0f, z);
      float u2 = __fmul_rn(u1, nn);
      float u3 = __fmul_rn(z, hp[j]);
      float h = __fadd_rn(u2, u3);
      hout[(size_t)n * Hdim + j] = h;
      A2[(size_t)n * 2 * Hdim + j] = h;
      hsh[j] = h;
    }
  }
  __syncthreads();

  const float* q = q_enc + (size_t)b * Lq * Hdim;
  if (t < Lq) {
    const float4* h4 = reinterpret_cast<const float4*>(hsh);
    const float4* q4 = reinterpret_cast<const float4*>(q + (size_t)t * Hdim);
    float acc[8];
#pragma unroll
    for (int j = 0; j < 8; ++j) acc[j] = 0.f;
    for (int i = 0; i < 128; ++i) {
      float4 ha = h4[2 * i], hb = h4[2 * i + 1];
      float4 qa = q4[2 * i], qb = q4[2 * i + 1];
      acc[0] = fmaf(ha.x, qa.x, acc[0]);
      acc[1] = fmaf(ha.y, qa.y, acc[1]);
      acc[2] = fmaf(ha.z, qa.z, acc[2]);
      acc[3] = fmaf(ha.w, qa.w, acc[3]);
      acc[4] = fmaf(hb.x, qb.x, acc[4]);
      acc[5] = fmaf(hb.y, qb.y, acc[5]);
      acc[6] = fmaf(hb.z, qb.z, acc[6]);
      acc[7] = fmaf(hb.w, qb.w, acc[7]);
    }
    float b0 = __fadd_rn(acc[0], acc[4]);
    float b1 = __fadd_rn(acc[1], acc[5]);
    float b2 = __fadd_rn(acc[2], acc[6]);
    float b3 = __fadd_rn(acc[3], acc[7]);
    float c0 = __fadd_rn(b0, b2);
    float c1 = __fadd_rn(b1, b3);
    float dot = __fadd_rn(c0, c1);
    att[t] = __fdiv_rn(dot, 32.0f);
  }
  __syncthreads();
  if (t == 0) {
    int len = q_len[b];
    float mx = -INFINITY;
    for (int l = 0; l < Lq; ++l) {
      float v = (l < len) ? att[l] : NEGF;
      att[l] = v;
      mx = fmaxf(mx, v);
    }
    s_mx = mx;
  }
  __syncthreads();
  if (t < Lq) ebuf[t] = exp_xla(__fsub_rn(att[t], s_mx));
  __syncthreads();
  if (t == 0) {
    float acc[8];
#pragma unroll
    for (int j = 0; j < 8; ++j) acc[j] = 0.f;
    for (int i = 0; i < 8; ++i) {
#pragma unroll
      for (int j = 0; j < 8; ++j) acc[j] = __fadd_rn(acc[j], ebuf[i * 8 + j]);
    }
    float b0 = __fadd_rn(acc[0], acc[4]);
    float b1 = __fadd_rn(acc[1], acc[5]);
    float b2 = __fadd_rn(acc[2], acc[6]);
    float b3 = __fadd_rn(acc[3], acc[7]);
    float c0 = __fadd_rn(b0, b2);
    float c1 = __fadd_rn(b1, b3);
    s_sum = __fadd_rn(c0, c1);
  }
  __syncthreads();
  if (t < Lq) att[t] = __fdiv_rn(ebuf[t], s_sum);
  __syncthreads();
#pragma unroll
  for (int hh = 0; hh < 4; ++hh) {
    int h = t + hh * 256;
    float c = 0.f;
    for (int l = 0; l < Lq; ++l) c = fmaf(att[l], q[(size_t)l * Hdim + h], c);
    A2[(size_t)n * 2 * Hdim + Hdim + h] = c;
  }
}

// ---- per-row max + XLA exp + 8-lane strided sum + Cephes log ----
__global__ __launch_bounds__(256) void lse_kernel(const float* __restrict__ logits,
                                                  float* __restrict__ ebuf,
                                                  float* __restrict__ mxA,
                                                  float* __restrict__ lseA)
{
  int n = blockIdx.x;
  const float* row = logits + (size_t)n * Vdim;
  float* erow = ebuf + (size_t)n * Vdim;
  int t = threadIdx.x;
  int lane = t & 63, w = t >> 6;
  const float4* row4 = reinterpret_cast<const float4*>(row);
  float4* erow4 = reinterpret_cast<float4*>(erow);
  float mx = -INFINITY;
  for (int i = t; i < 8000; i += 256) {
    float4 v = row4[i];
    mx = fmaxf(mx, fmaxf(fmaxf(v.x, v.y), fmaxf(v.z, v.w)));
  }
#pragma unroll
  for (int off = 32; off >= 1; off >>= 1) mx = fmaxf(mx, __shfl_xor(mx, off, 64));
  __shared__ float sm[4];
  __shared__ float lanes[8];
  if (lane == 0) sm[w] = mx;
  __syncthreads();
  mx = fmaxf(fmaxf(sm[0], sm[1]), fmaxf(sm[2], sm[3]));
  for (int i = t; i < 8000; i += 256) {
    float4 v = row4[i];
    float4 e;
    e.x = exp_xla(__fsub_rn(v.x, mx));
    e.y = exp_xla(__fsub_rn(v.y, mx));
    e.z = exp_xla(__fsub_rn(v.z, mx));
    e.w = exp_xla(__fsub_rn(v.w, mx));
    erow4[i] = e;
  }
  __syncthreads();
  if (t < 8) {
    float a = 0.f;
#pragma unroll 8
    for (int i = 0; i < 4000; ++i) a = __fadd_rn(a, erow[i * 8 + t]);
    lanes[t] = a;
  }
  __syncthreads();
  if (t == 0) {
    float b0 = __fadd_rn(lanes[0], lanes[4]);
    float b1 = __fadd_rn(lanes[1], lanes[5]);
    float b2 = __fadd_rn(lanes[2], lanes[6]);
    float b3 = __fadd_rn(lanes[3], lanes[7]);
    float c0 = __fadd_rn(b0, b2);
    float c1 = __fadd_rn(b1, b3);
    float s = __fadd_rn(c0, c1);
    mxA[n] = mx;
    lseA[n] = log_xla(s);
  }
}

// ---- per-batch top-8 over 8*32000 ----
__global__ __launch_bounds__(256) void topk_kernel(
    const float* __restrict__ logits, const float* __restrict__ mxA,
    const float* __restrict__ lseA, float* __restrict__ seq_scores,
    float* __restrict__ all_scores, int* __restrict__ all_preds,
    int* __restrict__ all_syms, int step)
{
  int b = blockIdx.x, t = threadIdx.x;
  __shared__ float s_seq[8], s_mx[8], s_lse[8];
  if (t < 8) {
    s_seq[t] = seq_scores[b * 8 + t];
    s_mx[t] = mxA[b * 8 + t];
    s_lse[t] = lseA[b * 8 + t];
  }
  __syncthreads();
  float lv[8]; int li[8];
#pragma unroll
  for (int r = 0; r < 8; ++r) { lv[r] = -INFINITY; li[r] = INT_MAX; }
  const float4* base4 = reinterpret_cast<const float4*>(logits + (size_t)b * 8 * Vdim);
  for (int c4 = t; c4 < 64000; c4 += 256) {
    float4 v4 = base4[c4];
    int cb = c4 * 4;
#pragma unroll
    for (int e = 0; e < 4; ++e) {
      int c = cb + e;
      int k = c / Vdim;
      float x = (e == 0) ? v4.x : (e == 1) ? v4.y : (e == 2) ? v4.z : v4.w;
      float sh = __fsub_rn(x, s_mx[k]);
      float lp = __fsub_rn(sh, s_lse[k]);
      float cand = __fadd_rn(s_seq[k], lp);
      if (betterf(cand, c, lv[7], li[7])) {
        lv[7] = cand; li[7] = c;
#pragma unroll
        for (int r = 7; r > 0; --r) {
          if (betterf(lv[r], li[r], lv[r - 1], li[r - 1])) {
            float tv = lv[r]; lv[r] = lv[r - 1]; lv[r - 1] = tv;
            int ti = li[r]; li[r] = li[r - 1]; li[r - 1] = ti;
          }
        }
      }
    }
  }
  __shared__ float sv[256][8];
  __shared__ int si[256][8];
#pragma unroll
  for (int r = 0; r < 8; ++r) { sv[t][r] = lv[r]; si[t][r] = li[r]; }
  __syncthreads();
  if (t == 0) {
    for (int u = 1; u < 256; ++u) {
#pragma unroll
      for (int r = 0; r < 8; ++r) {
        float v = sv[u][r]; int ix = si[u][r];
        if (betterf(v, ix, lv[7], li[7])) {
          lv[7] = v; li[7] = ix;
#pragma unroll
          for (int q = 7; q > 0; --q) {
            if (betterf(lv[q], li[q], lv[q - 1], li[q - 1])) {
              float tv = lv[q]; lv[q] = lv[q - 1]; lv[q - 1] = tv;
              int ti = li[q]; li[q] = li[q - 1]; li[q - 1] = ti;
            }
          }
        } else break;
      }
    }
#pragma unroll
    for (int r = 0; r < 8; ++r) {
      int idx = li[r];
      int sym = idx % Vdim;
      int pred = idx / Vdim + b * 8;
      int n = b * 8 + r;
      all_scores[step * Nrows + n] = lv[r];
      all_preds[step * Nrows + n] = pred;
      all_syms[step * Nrows + n] = sym;
      seq_scores[n] = (sym == 2) ? NEGF : lv[r];
    }
  }
}

__global__ void init_kernel(float* seq_scores, int* init_hmap, int* init_sym) {
  int t = threadIdx.x;
  if (t < 128) {
    seq_scores[t] = ((t & 7) == 0) ? 0.0f : NEGF;
    init_hmap[t] = t >> 3;
    init_sym[t] = 1;   // SOS
  }
}

__global__ void final_topk(const float* __restrict__ all_scores,
                           int* __restrict__ tpred, float* __restrict__ out_scores) {
  int b = threadIdx.x;
  if (b >= 16) return;
  float v[8]; int ki[8];
#pragma unroll
  for (int k = 0; k < 8; ++k) { v[k] = all_scores[63 * Nrows + b * 8 + k]; ki[k] = k; }
#pragma unroll
  for (int p = 0; p < 7; ++p)
#pragma unroll
    for (int i = 0; i < 7; ++i) {
      if (!betterf(v[i], ki[i], v[i + 1], ki[i + 1])) {
        float tv = v[i]; v[i] = v[i + 1]; v[i + 1] = tv;
        int ti = ki[i]; ki[i] = ki[i + 1]; ki[i + 1] = ti;
      }
    }
#pragma unroll
  for (int j = 0; j < 8; ++j) {
    out_scores[b * 8 + j] = v[j];
    tpred[b * 8 + j] = b * 8 + ki[j];
  }
}

__global__ void backtrack(const int* __restrict__ all_syms, const int* __restrict__ all_preds,
                          const int* __restrict__ tpred, float* __restrict__ out_seq) {
  int n = threadIdx.x;
  if (n >= 128) return;
  int carry = tpred[n];
  for (int tt = 63; tt >= 0; --tt) {
    int sym = all_syms[tt * Nrows + carry];
    out_seq[(size_t)n * 64 + tt] = (float)sym;
    carry = all_preds[tt * Nrows + carry];
  }
}

extern "C" void kernel_launch(void* const* d_in, const int* in_sizes, int n_in,
                              void* d_out, int out_size, void* d_ws, size_t ws_size,
                              hipStream_t stream) {
  (void)in_sizes; (void)n_in; (void)out_size; (void)ws_size;
  const float* dec_hidden = (const float*)d_in[0];
  const float* q_enc      = (const float*)d_in[1];
  const int*   q_len      = (const int*)d_in[2];
  const float* embedding  = (const float*)d_in[3];
  const float* W_ih       = (const float*)d_in[4];
  const float* W_hh       = (const float*)d_in[5];
  const float* b_ih       = (const float*)d_in[6];
  const float* b_hh       = (const float*)d_in[7];
  const float* W_c        = (const float*)d_in[8];
  const float* W_out      = (const float*)d_in[9];
  const float* b_out      = (const float*)d_in[10];
  float* out_scores = (float*)d_out;
  float* out_seq    = (float*)d_out + 128;

  char* w = (char*)d_ws;
  auto alloc = [&](size_t bytes) {
    char* p = w;
    w += (bytes + 255) & ~(size_t)255;
    return p;
  };
  float* hbuf0 = (float*)alloc((size_t)128 * 1024 * 4);
  float* hbuf1 = (float*)alloc((size_t)128 * 1024 * 4);
  float* A2    = (float*)alloc((size_t)128 * 2048 * 4);
  float* obuf  = (float*)alloc((size_t)128 * 1024 * 4);
  float* gA    = (float*)alloc((size_t)128 * 3072 * 4);
  float* gB    = (float*)alloc((size_t)128 * 3072 * 4);
  float* logits = (float*)alloc((size_t)128 * 32000 * 4);
  float* ebuf   = (float*)alloc((size_t)128 * 32000 * 4);
  float* mxA   = (float*)alloc(128 * 4);
  float* lseA  = (float*)alloc(128 * 4);
  float* seq_scores = (float*)alloc(128 * 4);
  int* init_hmap = (int*)alloc(128 * 4);
  int* init_sym  = (int*)alloc(128 * 4);
  int* tpred     = (int*)alloc(128 * 4);
  float* all_scores = (float*)alloc((size_t)64 * 128 * 4);
  int* all_preds = (int*)alloc((size_t)64 * 128 * 4);
  int* all_syms  = (int*)alloc((size_t)64 * 128 * 4);

  init_kernel<<<1, 128, 0, stream>>>(seq_scores, init_hmap, init_sym);

  for (int t = 0; t < TMAX; ++t) {
    const int* symmap = (t == 0) ? init_sym : (all_syms + (t - 1) * Nrows);
    const int* hmap   = (t == 0) ? init_hmap : (all_preds + (t - 1) * Nrows);
    const float* hprev = (t == 0) ? dec_hidden : (((t - 1) & 1) ? hbuf1 : hbuf0);
    float* hcur = (t & 1) ? hbuf1 : hbuf0;

    gates_gemm<<<dim3(48, 4, 2), 256, 0, stream>>>(
        embedding, symmap, W_ih, hprev, hmap, W_hh, gA, gB);
    gru_attn<<<128, 256, 0, stream>>>(gA, gB, b_ih, b_hh, hprev, hmap,
                                      q_enc, q_len, hcur, A2);
    sgemm_wc<<<dim3(32, 4), 256, 0, stream>>>(A2, W_c, obuf);
    sgemm_logits<<<250, 256, 0, stream>>>(obuf, W_out, b_out, logits);
    lse_kernel<<<128, 256, 0, stream>>>(logits, ebuf, mxA, lseA);
    topk_kernel<<<16, 256, 0, stream>>>(logits, mxA, lseA, seq_scores,
                                        all_scores, all_preds, all_syms, t);
  }

  final_topk<<<1, 128, 0, stream>>>(all_scores, tpred, out_scores);
  backtrack<<<1, 128, 0, stream>>>(all_syms, all_preds, tpred, out_seq);
}

// Round 19
// 60085.950 us; speedup vs baseline: 1.5374x; 1.5374x over previous
//
#include <hip/hip_runtime.h>
#include <cstdint>
#include <cstddef>
#include <climits>

#define Hdim 1024
#define Vdim 32000
#define Lq 64
#define Nrows 128
#define TMAX 64
#define NEGF (-1e30f)

// lower flat index wins ties (jax.lax.top_k stable semantics)
__device__ __forceinline__ bool betterf(float av, int ai, float bv, int bi) {
  return (av > bv) || (av == bv && ai < bi);
}

// ---- XLA CPU tanh f32 ----
__device__ __forceinline__ float tanh_xla(float x) {
  float ax = fabsf(x);
  float xc = fminf(fmaxf(x, -7.90531110763549805f), 7.90531110763549805f);
  float x2 = __fmul_rn(xc, xc);
  float p = -2.76076847742355e-16f;
  p = fmaf(p, x2, 2.00018790482477e-13f);
  p = fmaf(p, x2, -8.60467152213735e-11f);
  p = fmaf(p, x2, 5.12229709037114e-08f);
  p = fmaf(p, x2, 1.48572235717979e-05f);
  p = fmaf(p, x2, 6.37261928875436e-04f);
  p = fmaf(p, x2, 4.89352455891786e-03f);
  p = __fmul_rn(xc, p);
  float q = 1.19825839466702e-06f;
  q = fmaf(q, x2, 1.18534705686654e-04f);
  q = fmaf(q, x2, 2.26843463243900e-03f);
  q = fmaf(q, x2, 4.89352518554385e-03f);
  float r = __fdiv_rn(p, q);
  return (ax < 0.0004f) ? x : r;
}

// ---- XLA LogisticExpander ----
__device__ __forceinline__ float sigmoid_xla(float x) {
  return __fadd_rn(0.5f, __fmul_rn(0.5f, tanh_xla(__fmul_rn(0.5f, x))));
}

// ---- Eigen/Cephes pexp f32 ----
__device__ __forceinline__ float exp_xla(float x) {
  x = fminf(x, 88.3762626647950f);
  x = fmaxf(x, -88.3762626647949f);
  float m = floorf(fmaf(x, 1.44269504088896341f, 0.5f));
  float r = fmaf(m, -0.693359375f, x);
  r = fmaf(m, 2.12194440e-4f, r);
  float r2 = __fmul_rn(r, r);
  float p = 1.9875691500e-4f;
  p = fmaf(p, r, 1.3981999507e-3f);
  p = fmaf(p, r, 8.3334519073e-3f);
  p = fmaf(p, r, 4.1665795894e-2f);
  p = fmaf(p, r, 1.6666665459e-1f);
  p = fmaf(p, r, 5.0000001201e-1f);
  p = fmaf(p, r2, r);
  p = __fadd_rn(p, 1.0f);
  int n = (int)m;
  float two_n = __int_as_float((n + 127) << 23);
  return __fmul_rn(p, two_n);
}

// ---- Cephes logf ----
__device__ __forceinline__ float log_xla(float x) {
  int ix = __float_as_int(x);
  int e = ((ix >> 23) & 0xFF) - 126;
  float m = __int_as_float((ix & 0x007FFFFF) | 0x3F000000);
  if (m < 0.707106781186547524f) { e -= 1; m = __fadd_rn(m, m); }
  m = __fsub_rn(m, 1.0f);
  float z = __fmul_rn(m, m);
  float p = 7.0376836292e-2f;
  p = fmaf(p, m, -1.1514610310e-1f);
  p = fmaf(p, m, 1.1676998740e-1f);
  p = fmaf(p, m, -1.2420140846e-1f);
  p = fmaf(p, m, 1.4249322787e-1f);
  p = fmaf(p, m, -1.6668057665e-1f);
  p = fmaf(p, m, 2.0000714765e-1f);
  p = fmaf(p, m, -2.4999993993e-1f);
  p = fmaf(p, m, 3.3333331174e-1f);
  float ef = (float)e;
  float y = __fmul_rn(m, __fmul_rn(z, p));
  y = fmaf(ef, -2.12194440e-4f, y);
  y = fmaf(z, -0.5f, y);
  float res = __fadd_rn(m, y);
  res = fmaf(ef, 0.693359375f, res);
  return res;
}

// B-column XOR swizzle (16B-aligned permutation)
__device__ __forceinline__ int bswz(int col) {
  return col ^ (((col >> 5) & 3) << 2);
}

// ---- templated GEMM body (256 threads, single-buffered LDS, r15 structure) ----
template <int MT, int NT>
__device__ __forceinline__ void gemm_body(
    const float* __restrict__ A, int lda, const int* __restrict__ rowmap,
    const float* __restrict__ B, int ldb, const float* __restrict__ bias,
    float* __restrict__ C, int ldc, int K, int act, int n0, int m0)
{
  constexpr int RM = MT / 16, RN = NT / 16;
  constexpr int PA = MT + 4, PB = NT + 4;
  __shared__ float As[32][PA];
  __shared__ float Bs[32][PB];
  __shared__ int rows[MT];
  const int t = threadIdx.x;
  if (t < MT) rows[t] = rowmap ? rowmap[m0 + t] : (m0 + t);
  __syncthreads();
  const int tm = t >> 4, tn = t & 15;
  float acc[RM][RN] = {};
  for (int kt = 0; kt < K; kt += 32) {
#pragma unroll
    for (int i = 0; i < MT / 32; ++i) {
      int idx = t + i * 256;
      int m = idx >> 3, k4 = idx & 7;
      float4 v = *reinterpret_cast<const float4*>(
          &A[(size_t)rows[m] * lda + (size_t)(kt + k4 * 4)]);
      As[k4 * 4 + 0][m] = v.x;
      As[k4 * 4 + 1][m] = v.y;
      As[k4 * 4 + 2][m] = v.z;
      As[k4 * 4 + 3][m] = v.w;
    }
#pragma unroll
    for (int i = 0; i < NT / 32; ++i) {
      int idx = t + i * 256;
      int kk = idx / (NT / 4), n4 = idx % (NT / 4);
      float4 v = *reinterpret_cast<const float4*>(
          &B[(size_t)(kt + kk) * ldb + (size_t)(n0 + n4 * 4)]);
      *reinterpret_cast<float4*>(&Bs[kk][bswz(n4 * 4)]) = v;
    }
    __syncthreads();
#pragma unroll
    for (int kk = 0; kk < 32; ++kk) {
      float a[RM], bb[RN];
      if constexpr (RM == 2) {
        float2 v = *reinterpret_cast<const float2*>(&As[kk][tm * 2]);
        a[0] = v.x; a[1] = v.y;
      } else {
#pragma unroll
        for (int c = 0; c < RM / 4; ++c) {
          float4 v = *reinterpret_cast<const float4*>(&As[kk][tm * RM + c * 4]);
          a[c * 4 + 0] = v.x; a[c * 4 + 1] = v.y;
          a[c * 4 + 2] = v.z; a[c * 4 + 3] = v.w;
        }
      }
      if constexpr (RN == 2) {
        // NT==32 -> bswz is identity on cols <32; direct float2 read
        float2 v = *reinterpret_cast<const float2*>(&Bs[kk][tn * 2]);
        bb[0] = v.x; bb[1] = v.y;
      } else {
#pragma unroll
        for (int c = 0; c < RN / 4; ++c) {
          float4 v = *reinterpret_cast<const float4*>(
              &Bs[kk][bswz(tn * RN + c * 4)]);
          bb[c * 4 + 0] = v.x; bb[c * 4 + 1] = v.y;
          bb[c * 4 + 2] = v.z; bb[c * 4 + 3] = v.w;
        }
      }
#pragma unroll
      for (int i = 0; i < RM; ++i)
#pragma unroll
        for (int j = 0; j < RN; ++j)
          acc[i][j] = fmaf(a[i], bb[j], acc[i][j]);
    }
    __syncthreads();
  }
#pragma unroll
  for (int i = 0; i < RM; ++i) {
    int m = m0 + tm * RM + i;
#pragma unroll
    for (int j = 0; j < RN; ++j) {
      int n = n0 + tn * RN + j;
      float v = acc[i][j];
      if (bias) v = __fadd_rn(v, bias[n]);
      if (act == 1) v = tanh_xla(v);
      C[(size_t)m * ldc + n] = v;
    }
  }
}

// logits: 128x128 tile, 8x8 micro, grid 250
__global__ __launch_bounds__(256) void sgemm_logits(
    const float* __restrict__ A, const float* __restrict__ B,
    const float* __restrict__ bias, float* __restrict__ C)
{
  gemm_body<128, 128>(A, 1024, nullptr, B, 32000, bias, C, 32000, 1024, 0,
                      blockIdx.x * 128, 0);
}

// both gate GEMMs in one launch: 32x64 tiles -> grid (48,4,2) = 384 blocks
__global__ __launch_bounds__(256) void gates_gemm(
    const float* __restrict__ emb, const int* __restrict__ symmap,
    const float* __restrict__ W_ih,
    const float* __restrict__ hprev, const int* __restrict__ hmap,
    const float* __restrict__ W_hh,
    float* __restrict__ gA, float* __restrict__ gB)
{
  if (blockIdx.z == 0)
    gemm_body<32, 64>(emb, 1024, symmap, W_ih, 3072, nullptr, gA, 3072, 1024, 0,
                      blockIdx.x * 64, blockIdx.y * 32);
  else
    gemm_body<32, 64>(hprev, 1024, hmap, W_hh, 3072, nullptr, gB, 3072, 1024, 0,
                      blockIdx.x * 64, blockIdx.y * 32);
}

// W_c GEMM + tanh: 32x32 tiles -> grid (32,4) = 128 blocks
__global__ __launch_bounds__(256) void sgemm_wc(
    const float* __restrict__ A2, const float* __restrict__ W_c,
    float* __restrict__ obuf)
{
  gemm_body<32, 32>(A2, 2048, nullptr, W_c, 1024, nullptr, obuf, 1024, 2048, 1,
                    blockIdx.x * 32, blockIdx.y * 32);
}

// ---- fused GRU gates + attention (block n computes full h row, then attn) ----
__global__ __launch_bounds__(256) void gru_attn(
    const float* __restrict__ gA, const float* __restrict__ gB,
    const float* __restrict__ b_ih, const float* __restrict__ b_hh,
    const float* __restrict__ hprev, const int* __restrict__ hmap,
    const float* __restrict__ q_enc, const int* __restrict__ q_len,
    float* __restrict__ hout, float* __restrict__ A2)
{
  int n = blockIdx.x;
  int b = n >> 3;
  int t = threadIdx.x;
  __shared__ float hsh[Hdim];
  __shared__ float att[Lq];
  __shared__ float ebuf[Lq];
  __shared__ float s_mx, s_sum;

  {
    int row = hmap[n];
    const float* hp = hprev + (size_t)row * Hdim;
    const float* a = gA + (size_t)n * 3 * Hdim;
    const float* g = gB + (size_t)n * 3 * Hdim;
    for (int j = t; j < Hdim; j += 256) {
      float xr = __fadd_rn(a[j],            b_ih[j]);
      float xz = __fadd_rn(a[Hdim + j],     b_ih[Hdim + j]);
      float xn = __fadd_rn(a[2 * Hdim + j], b_ih[2 * Hdim + j]);
      float hr = __fadd_rn(g[j],            b_hh[j]);
      float hz = __fadd_rn(g[Hdim + j],     b_hh[Hdim + j]);
      float hn = __fadd_rn(g[2 * Hdim + j], b_hh[2 * Hdim + j]);
      float r = sigmoid_xla(__fadd_rn(xr, hr));
      float z = sigmoid_xla(__fadd_rn(xz, hz));
      float t1 = __fmul_rn(r, hn);
      float nn = tanh_xla(__fadd_rn(xn, t1));
      float u1 = __fsub_rn(1.0f, z);
      float u2 = __fmul_rn(u1, nn);
      float u3 = __fmul_rn(z, hp[j]);
      float h = __fadd_rn(u2, u3);
      hout[(size_t)n * Hdim + j] = h;
      A2[(size_t)n * 2 * Hdim + j] = h;
      hsh[j] = h;
    }
  }
  __syncthreads();

  const float* q = q_enc + (size_t)b * Lq * Hdim;
  if (t < Lq) {
    const float4* h4 = reinterpret_cast<const float4*>(hsh);
    const float4* q4 = reinterpret_cast<const float4*>(q + (size_t)t * Hdim);
    float acc[8];
#pragma unroll
    for (int j = 0; j < 8; ++j) acc[j] = 0.f;
    for (int i = 0; i < 128; ++i) {
      float4 ha = h4[2 * i], hb = h4[2 * i + 1];
      float4 qa = q4[2 * i], qb = q4[2 * i + 1];
      acc[0] = fmaf(ha.x, qa.x, acc[0]);
      acc[1] = fmaf(ha.y, qa.y, acc[1]);
      acc[2] = fmaf(ha.z, qa.z, acc[2]);
      acc[3] = fmaf(ha.w, qa.w, acc[3]);
      acc[4] = fmaf(hb.x, qb.x, acc[4]);
      acc[5] = fmaf(hb.y, qb.y, acc[5]);
      acc[6] = fmaf(hb.z, qb.z, acc[6]);
      acc[7] = fmaf(hb.w, qb.w, acc[7]);
    }
    float b0 = __fadd_rn(acc[0], acc[4]);
    float b1 = __fadd_rn(acc[1], acc[5]);
    float b2 = __fadd_rn(acc[2], acc[6]);
    float b3 = __fadd_rn(acc[3], acc[7]);
    float c0 = __fadd_rn(b0, b2);
    float c1 = __fadd_rn(b1, b3);
    float dot = __fadd_rn(c0, c1);
    att[t] = __fdiv_rn(dot, 32.0f);
  }
  __syncthreads();
  if (t == 0) {
    int len = q_len[b];
    float mx = -INFINITY;
    for (int l = 0; l < Lq; ++l) {
      float v = (l < len) ? att[l] : NEGF;
      att[l] = v;
      mx = fmaxf(mx, v);
    }
    s_mx = mx;
  }
  __syncthreads();
  if (t < Lq) ebuf[t] = exp_xla(__fsub_rn(att[t], s_mx));
  __syncthreads();
  if (t == 0) {
    float acc[8];
#pragma unroll
    for (int j = 0; j < 8; ++j) acc[j] = 0.f;
    for (int i = 0; i < 8; ++i) {
#pragma unroll
      for (int j = 0; j < 8; ++j) acc[j] = __fadd_rn(acc[j], ebuf[i * 8 + j]);
    }
    float b0 = __fadd_rn(acc[0], acc[4]);
    float b1 = __fadd_rn(acc[1], acc[5]);
    float b2 = __fadd_rn(acc[2], acc[6]);
    float b3 = __fadd_rn(acc[3], acc[7]);
    float c0 = __fadd_rn(b0, b2);
    float c1 = __fadd_rn(b1, b3);
    s_sum = __fadd_rn(c0, c1);
  }
  __syncthreads();
  if (t < Lq) att[t] = __fdiv_rn(ebuf[t], s_sum);
  __syncthreads();
#pragma unroll
  for (int hh = 0; hh < 4; ++hh) {
    int h = t + hh * 256;
    float c = 0.f;
    for (int l = 0; l < Lq; ++l) c = fmaf(att[l], q[(size_t)l * Hdim + h], c);
    A2[(size_t)n * 2 * Hdim + Hdim + h] = c;
  }
}

// ---- per-row max (order-free) + XLA exp + 8-lane strided sum + Cephes log ----
__global__ __launch_bounds__(256) void lse_kernel(const float* __restrict__ logits,
                                                  float* __restrict__ ebuf,
                                                  float* __restrict__ mxA,
                                                  float* __restrict__ lseA)
{
  int n = blockIdx.x;
  const float* row = logits + (size_t)n * Vdim;
  float* erow = ebuf + (size_t)n * Vdim;
  int t = threadIdx.x;
  int lane = t & 63, w = t >> 6;
  const float4* row4 = reinterpret_cast<const float4*>(row);
  float4* erow4 = reinterpret_cast<float4*>(erow);
  float mx = -INFINITY;
  for (int i = t; i < 8000; i += 256) {
    float4 v = row4[i];
    mx = fmaxf(mx, fmaxf(fmaxf(v.x, v.y), fmaxf(v.z, v.w)));
  }
#pragma unroll
  for (int off = 32; off >= 1; off >>= 1) mx = fmaxf(mx, __shfl_xor(mx, off, 64));
  __shared__ float sm[4];
  __shared__ float lanes[8];
  if (lane == 0) sm[w] = mx;
  __syncthreads();
  mx = fmaxf(fmaxf(sm[0], sm[1]), fmaxf(sm[2], sm[3]));
  for (int i = t; i < 8000; i += 256) {
    float4 v = row4[i];
    float4 e;
    e.x = exp_xla(__fsub_rn(v.x, mx));
    e.y = exp_xla(__fsub_rn(v.y, mx));
    e.z = exp_xla(__fsub_rn(v.z, mx));
    e.w = exp_xla(__fsub_rn(v.w, mx));
    erow4[i] = e;
  }
  __syncthreads();
  if (t < 8) {
    float a = 0.f;
#pragma unroll 8
    for (int i = 0; i < 4000; ++i) a = __fadd_rn(a, erow[i * 8 + t]);
    lanes[t] = a;
  }
  __syncthreads();
  if (t == 0) {
    float b0 = __fadd_rn(lanes[0], lanes[4]);
    float b1 = __fadd_rn(lanes[1], lanes[5]);
    float b2 = __fadd_rn(lanes[2], lanes[6]);
    float b3 = __fadd_rn(lanes[3], lanes[7]);
    float c0 = __fadd_rn(b0, b2);
    float c1 = __fadd_rn(b1, b3);
    float s = __fadd_rn(c0, c1);
    mxA[n] = mx;
    lseA[n] = log_xla(s);
  }
}

// ---- per-batch top-8 over 8*32000 (float4 stripe; set-based => order-safe) ----
__global__ __launch_bounds__(256) void topk_kernel(
    const float* __restrict__ logits, const float* __restrict__ mxA,
    const float* __restrict__ lseA, float* __restrict__ seq_scores,
    float* __restrict__ all_scores, int* __restrict__ all_preds,
    int* __restrict__ all_syms, int step)
{
  int b = blockIdx.x, t = threadIdx.x;
  __shared__ float s_seq[8], s_mx[8], s_lse[8];
  if (t < 8) {
    s_seq[t] = seq_scores[b * 8 + t];
    s_mx[t] = mxA[b * 8 + t];
    s_lse[t] = lseA[b * 8 + t];
  }
  __syncthreads();
  float lv[8]; int li[8];
#pragma unroll
  for (int r = 0; r < 8; ++r) { lv[r] = -INFINITY; li[r] = INT_MAX; }
  const float4* base4 = reinterpret_cast<const float4*>(logits + (size_t)b * 8 * Vdim);
  for (int c4 = t; c4 < 64000; c4 += 256) {
    float4 v4 = base4[c4];
    int cb = c4 * 4;
#pragma unroll
    for (int e = 0; e < 4; ++e) {
      int c = cb + e;
      int k = c / Vdim;
      float x = (e == 0) ? v4.x : (e == 1) ? v4.y : (e == 2) ? v4.z : v4.w;
      float sh = __fsub_rn(x, s_mx[k]);
      float lp = __fsub_rn(sh, s_lse[k]);
      float cand = __fadd_rn(s_seq[k], lp);
      if (betterf(cand, c, lv[7], li[7])) {
        lv[7] = cand; li[7] = c;
#pragma unroll
        for (int r = 7; r > 0; --r) {
          if (betterf(lv[r], li[r], lv[r - 1], li[r - 1])) {
            float tv = lv[r]; lv[r] = lv[r - 1]; lv[r - 1] = tv;
            int ti = li[r]; li[r] = li[r - 1]; li[r - 1] = ti;
          }
        }
      }
    }
  }
  __shared__ float sv[256][8];
  __shared__ int si[256][8];
#pragma unroll
  for (int r = 0; r < 8; ++r) { sv[t][r] = lv[r]; si[t][r] = li[r]; }
  __syncthreads();
  if (t == 0) {
    for (int u = 1; u < 256; ++u) {
#pragma unroll
      for (int r = 0; r < 8; ++r) {
        float v = sv[u][r]; int ix = si[u][r];
        if (betterf(v, ix, lv[7], li[7])) {
          lv[7] = v; li[7] = ix;
#pragma unroll
          for (int q = 7; q > 0; --q) {
            if (betterf(lv[q], li[q], lv[q - 1], li[q - 1])) {
              float tv = lv[q]; lv[q] = lv[q - 1]; lv[q - 1] = tv;
              int ti = li[q]; li[q] = li[q - 1]; li[q - 1] = ti;
            }
          }
        } else break;
      }
    }
#pragma unroll
    for (int r = 0; r < 8; ++r) {
      int idx = li[r];
      int sym = idx % Vdim;
      int pred = idx / Vdim + b * 8;
      int n = b * 8 + r;
      all_scores[step * Nrows + n] = lv[r];
      all_preds[step * Nrows + n] = pred;
      all_syms[step * Nrows + n] = sym;
      seq_scores[n] = (sym == 2) ? NEGF : lv[r];
    }
  }
}

__global__ void init_kernel(float* seq_scores, int* init_hmap, int* init_sym) {
  int t = threadIdx.x;
  if (t < 128) {
    seq_scores[t] = ((t & 7) == 0) ? 0.0f : NEGF;
    init_hmap[t] = t >> 3;
    init_sym[t] = 1;   // SOS
  }
}

__global__ void final_topk(const float* __restrict__ all_scores,
                           int* __restrict__ tpred, float* __restrict__ out_scores) {
  int b = threadIdx.x;
  if (b >= 16) return;
  float v[8]; int ki[8];
#pragma unroll
  for (int k = 0; k < 8; ++k) { v[k] = all_scores[63 * Nrows + b * 8 + k]; ki[k] = k; }
#pragma unroll
  for (int p = 0; p < 7; ++p)
#pragma unroll
    for (int i = 0; i < 7; ++i) {
      if (!betterf(v[i], ki[i], v[i + 1], ki[i + 1])) {
        float tv = v[i]; v[i] = v[i + 1]; v[i + 1] = tv;
        int ti = ki[i]; ki[i] = ki[i + 1]; ki[i + 1] = ti;
      }
    }
#pragma unroll
  for (int j = 0; j < 8; ++j) {
    out_scores[b * 8 + j] = v[j];
    tpred[b * 8 + j] = b * 8 + ki[j];
  }
}

__global__ void backtrack(const int* __restrict__ all_syms, const int* __restrict__ all_preds,
                          const int* __restrict__ tpred, float* __restrict__ out_seq) {
  int n = threadIdx.x;
  if (n >= 128) return;
  int carry = tpred[n];
  for (int tt = 63; tt >= 0; --tt) {
    int sym = all_syms[tt * Nrows + carry];
    out_seq[(size_t)n * 64 + tt] = (float)sym;
    carry = all_preds[tt * Nrows + carry];
  }
}

extern "C" void kernel_launch(void* const* d_in, const int* in_sizes, int n_in,
                              void* d_out, int out_size, void* d_ws, size_t ws_size,
                              hipStream_t stream) {
  (void)in_sizes; (void)n_in; (void)out_size; (void)ws_size;
  const float* dec_hidden = (const float*)d_in[0];
  const float* q_enc      = (const float*)d_in[1];
  const int*   q_len      = (const int*)d_in[2];
  const float* embedding  = (const float*)d_in[3];
  const float* W_ih       = (const float*)d_in[4];
  const float* W_hh       = (const float*)d_in[5];
  const float* b_ih       = (const float*)d_in[6];
  const float* b_hh       = (const float*)d_in[7];
  const float* W_c        = (const float*)d_in[8];
  const float* W_out      = (const float*)d_in[9];
  const float* b_out      = (const float*)d_in[10];
  float* out_scores = (float*)d_out;
  float* out_seq    = (float*)d_out + 128;

  char* w = (char*)d_ws;
  auto alloc = [&](size_t bytes) {
    char* p = w;
    w += (bytes + 255) & ~(size_t)255;
    return p;
  };
  float* hbuf0 = (float*)alloc((size_t)128 * 1024 * 4);
  float* hbuf1 = (float*)alloc((size_t)128 * 1024 * 4);
  float* A2    = (float*)alloc((size_t)128 * 2048 * 4);
  float* obuf  = (float*)alloc((size_t)128 * 1024 * 4);
  float* gA    = (float*)alloc((size_t)128 * 3072 * 4);
  float* gB    = (float*)alloc((size_t)128 * 3072 * 4);
  float* logits = (float*)alloc((size_t)128 * 32000 * 4);
  float* ebuf   = (float*)alloc((size_t)128 * 32000 * 4);
  float* mxA   = (float*)alloc(128 * 4);
  float* lseA  = (float*)alloc(128 * 4);
  float* seq_scores = (float*)alloc(128 * 4);
  int* init_hmap = (int*)alloc(128 * 4);
  int* init_sym  = (int*)alloc(128 * 4);
  int* tpred     = (int*)alloc(128 * 4);
  float* all_scores = (float*)alloc((size_t)64 * 128 * 4);
  int* all_preds = (int*)alloc((size_t)64 * 128 * 4);
  int* all_syms  = (int*)alloc((size_t)64 * 128 * 4);

  init_kernel<<<1, 128, 0, stream>>>(seq_scores, init_hmap, init_sym);

  for (int t = 0; t < TMAX; ++t) {
    const int* symmap = (t == 0) ? init_sym : (all_syms + (t - 1) * Nrows);
    const int* hmap   = (t == 0) ? init_hmap : (all_preds + (t - 1) * Nrows);
    const float* hprev = (t == 0) ? dec_hidden : (((t - 1) & 1) ? hbuf1 : hbuf0);
    float* hcur = (t & 1) ? hbuf1 : hbuf0;

    gates_gemm<<<dim3(48, 4, 2), 256, 0, stream>>>(
        embedding, symmap, W_ih, hprev, hmap, W_hh, gA, gB);
    gru_attn<<<128, 256, 0, stream>>>(gA, gB, b_ih, b_hh, hprev, hmap,
                                      q_enc, q_len, hcur, A2);
    sgemm_wc<<<dim3(32, 4), 256, 0, stream>>>(A2, W_c, obuf);
    sgemm_logits<<<250, 256, 0, stream>>>(obuf, W_out, b_out, logits);
    lse_kernel<<<128, 256, 0, stream>>>(logits, ebuf, mxA, lseA);
    topk_kernel<<<16, 256, 0, stream>>>(logits, mxA, lseA, seq_scores,
                                        all_scores, all_preds, all_syms, t);
  }

  final_topk<<<1, 128, 0, stream>>>(all_scores, tpred, out_scores);
  backtrack<<<1, 128, 0, stream>>>(all_syms, all_preds, tpred, out_seq);
}